// Round 4
// baseline (272.250 us; speedup 1.0000x reference)
//
#include <hip/hip_runtime.h>

#define B_ 4
#define T_ 2048
#define D_ 1024
#define H_ 16
#define S_ 64

typedef __attribute__((ext_vector_type(8))) short bf16x8;
typedef __attribute__((ext_vector_type(16))) float f32x16;
typedef unsigned int uint;

__device__ __forceinline__ short f2bf(float f) {
    union { float f; uint u; } v; v.f = f;
    uint r = v.u + 0x7fffu + ((v.u >> 16) & 1u);   // RNE
    return (short)(r >> 16);
}

// async global->LDS, 16B per lane; LDS dst = wave-uniform base + lane*16
__device__ __forceinline__ void gld16(const short* g, short* l) {
    __builtin_amdgcn_global_load_lds((const __attribute__((address_space(1))) void*)g,
                                     (__attribute__((address_space(3))) void*)l, 16, 0, 0);
}

// ---------------- fused fp32->bf16 prepass: x, Wq, Wu ----------------
__global__ __launch_bounds__(256) void cvt3(const float* __restrict__ x,
                                            const float* __restrict__ wq,
                                            const float* __restrict__ wu,
                                            short* __restrict__ xb,
                                            short* __restrict__ wqb,
                                            short* __restrict__ wub) {
    const int NX = B_ * T_ * D_ / 8;   // 1048576 8-elem units
    const int NW = D_ * D_ / 8;        // 131072
    int i = blockIdx.x * 256 + threadIdx.x;
    const float* src; short* dst; int off;
    if (i < NX)            { src = x;  dst = xb;  off = i; }
    else if (i < NX + NW)  { src = wq; dst = wqb; off = i - NX; }
    else                   { src = wu; dst = wub; off = i - NX - NW; }
    float4 a = *(const float4*)(src + (size_t)off * 8);
    float4 b = *(const float4*)(src + (size_t)off * 8 + 4);
    short o[8] = {f2bf(a.x), f2bf(a.y), f2bf(a.z), f2bf(a.w),
                  f2bf(b.x), f2bf(b.y), f2bf(b.z), f2bf(b.w)};
    *(bf16x8*)(dst + (size_t)off * 8) = *(bf16x8*)o;
}

// ---------------- bf16 MFMA GEMM, 128x64 tile, 4 blocks/CU ------------------
// C[M,N] = A[M,K] @ Bt[N,K]^T (+bias). BK=32, 4 waves (2 wm x 2 wn), each
// wave owns a 64x32 output (acc = 2 x f32x16 = 32 VGPR). Grid doubles to
// 1024 blocks -> 4 blocks/CU (was 2): the r0/r1 nulls showed the kernel is
// latency/barrier-bound with no co-resident waves to hide it (m102 curve:
// 1/CU=320TF, 4/CU=833TF). 3-deep global_load_lds pipeline, counted vmcnt.
#define STAGE_G(t, bi) do {                                                       \
        int kk_ = (t) << 5;                                                       \
        gld16(Ap + (size_t)lane * K        + kk_ + wv * 8, &As[bi][(wv * 128) * 8]);      \
        gld16(Ap + (size_t)(64 + lane) * K + kk_ + wv * 8, &As[bi][(wv * 128 + 64) * 8]); \
        gld16(Bp + (size_t)lane * K        + kk_ + wv * 8, &Bs[bi][(wv * 64) * 8]);       \
    } while (0)

template <bool OUT_BF16>
__global__ __launch_bounds__(256, 4) void gemm_bt(const short* __restrict__ A,
                                                  const short* __restrict__ Bt,
                                                  const float* __restrict__ bias,
                                                  void* __restrict__ Cv,
                                                  int M, int N, int K) {
    __shared__ short As[3][4096];   // 3 x 8 KB  (A tile 128 x 32)
    __shared__ short Bs[3][2048];   // 3 x 4 KB  (B tile  64 x 32)
    const int tid  = threadIdx.x;
    const int lane = tid & 63;
    const int wv   = tid >> 6;
    const int wm   = wv >> 1, wn = wv & 1;
    const int h32  = lane >> 5;

    // bijective XCD swizzle (nbx*nby multiple of 8); each XCD gets nby/8
    // contiguous m-panels x all n-blocks -> 4MB working set, L2-resident.
    int bx = blockIdx.x, by = blockIdx.y;
    {
        const int nbx = gridDim.x, nby = gridDim.y;
        if ((nby & 7) == 0) {
            int f = blockIdx.x + nbx * blockIdx.y;
            int xcd = f & 7, slot = f >> 3;
            bx = slot % nbx;
            by = xcd * (nby >> 3) + slot / nbx;
        }
    }
    const int m0 = by * 128, n0 = bx * 64;
    const short* Ap = A + (size_t)m0 * K;
    const short* Bp = Bt + (size_t)n0 * K;

    f32x16 acc[2];
    #pragma unroll
    for (int i = 0; i < 2; ++i)
        #pragma unroll
        for (int r = 0; r < 16; ++r) acc[i][r] = 0.f;

    const int nt = K >> 5;           // 32 K-steps (K=1024)
    STAGE_G(0, 0);
    STAGE_G(1, 1);
    STAGE_G(2, 2);                   // 9 gld16/wave in flight

    int bi = 0;
    for (int t = 0; t < nt; ++t) {
        // wait until tile t's 3 loads (oldest) have landed; keep rest in flight
        if (t + 2 < nt)      asm volatile("s_waitcnt vmcnt(6)" ::: "memory");
        else if (t + 1 < nt) asm volatile("s_waitcnt vmcnt(3)" ::: "memory");
        else                 asm volatile("s_waitcnt vmcnt(0)" ::: "memory");
        __builtin_amdgcn_s_barrier();          // all waves' tile-t chunks landed
        asm volatile("" ::: "memory");

        const short* Ab = As[bi];
        const short* Bb = Bs[bi];
        #pragma unroll
        for (int ks2 = 0; ks2 < 2; ++ks2) {
            const int kk8 = ks2 * 2 + h32;
            bf16x8 af0 = *(bf16x8*)&Ab[(kk8 * 128 + wm * 64 + (lane & 31)) * 8];
            bf16x8 af1 = *(bf16x8*)&Ab[(kk8 * 128 + wm * 64 + 32 + (lane & 31)) * 8];
            bf16x8 bfr = *(bf16x8*)&Bb[(kk8 * 64 + wn * 32 + (lane & 31)) * 8];
            acc[0] = __builtin_amdgcn_mfma_f32_32x32x16_bf16(af0, bfr, acc[0], 0, 0, 0);
            acc[1] = __builtin_amdgcn_mfma_f32_32x32x16_bf16(af1, bfr, acc[1], 0, 0, 0);
        }

        asm volatile("" ::: "memory");
        __builtin_amdgcn_s_barrier();          // all waves done reading buffer bi
        if (t + 3 < nt) STAGE_G(t + 3, bi);    // refill the buffer just freed
        bi = (bi == 2) ? 0 : bi + 1;
    }

    const int col = n0 + wn * 32 + (lane & 31);
    float bv = 0.f;
    if (!OUT_BF16 && bias) bv = bias[col];
    #pragma unroll
    for (int mt = 0; mt < 2; ++mt) {
        const int rbase = m0 + wm * 64 + mt * 32;
        #pragma unroll
        for (int r = 0; r < 16; ++r) {
            int row = rbase + (r & 3) + 8 * (r >> 2) + 4 * h32;
            if constexpr (OUT_BF16)
                ((short*)Cv)[(size_t)row * N + col] = f2bf(acc[mt][r]);
            else
                ((float*)Cv)[(size_t)row * N + col] = acc[mt][r] + bv;
        }
    }
}

// ---------------- MFMA attention v5: VALU-trimmed softmax -------------------
// (unchanged from round 3 — clean attribution of the GEMM change)
__global__ __launch_bounds__(256, 3) void attn_mfma(const short* __restrict__ q,
                                                    short* __restrict__ o) {
    __shared__ short smem[16384];   // 32 KB: buf0=[0,8192), buf1=[8192,16384) shorts
    const int tid  = threadIdx.x;
    const int lane = tid & 63;
    const int wv   = tid >> 6;
    const int h32  = lane >> 5;
    const int b  = blockIdx.y >> 4;
    const int hh = blockIdx.y & 15;
    const int t0 = blockIdx.x * 128;
    const short* qb = q + (size_t)b * (T_ * D_) + hh * S_;

    // tile-invariant staging geometry
    const int c8  = tid & 7;
    const int uu0 = tid >> 3;            // 0..31
    const int uu1 = uu0 + 32;            // 32..63
    const int u_0 = (uu0 & 0x33) | ((uu0 & 4) << 1) | ((uu0 & 8) >> 1);  // b2<->b3
    const int u_1 = (uu1 & 0x33) | ((uu1 & 4) << 1) | ((uu1 & 8) >> 1);
    const int kfo0 = (c8 * 64 + (u_0 ^ c8)) * 8;          // Kf within buffer
    const int kfo1 = (c8 * 64 + (u_1 ^ c8)) * 8;
    const int kto0 = 4096 + (u_0 >> 4) * 1024 + ((u_0 >> 2) & 1) * 512 + (c8 >> 2) * 8
                   + ((u_0 & 3) | (((u_0 >> 3) & 1) << 2)) + (c8 & 3) * 16;
    const int kto1 = 4096 + (u_1 >> 4) * 1024 + ((u_1 >> 2) & 1) * 512 + (c8 >> 2) * 8
                   + ((u_1 & 3) | (((u_1 >> 3) & 1) << 2)) + (c8 & 3) * 16;
    const short* g0 = qb + (size_t)u_0 * D_ + c8 * 8;
    const short* g1 = qb + (size_t)u_1 * D_ + c8 * 8;

    // ---- prologue: issue tile-0 loads, stage Q, read Q frags ----
    bf16x8 st0 = *(const bf16x8*)g0;            // tile 0 (u0 = 0)
    bf16x8 st1 = *(const bf16x8*)g1;
    #pragma unroll
    for (int rep = 0; rep < 4; ++rep) {
        int f = rep * 256 + tid;
        int r = f >> 3, cq = f & 7;
        bf16x8 v = *(const bf16x8*)(qb + (size_t)(t0 + r) * D_ + cq * 8);
        *(bf16x8*)&smem[(cq * 128 + (r ^ cq)) * 8] = v;
    }
    __syncthreads();
    bf16x8 Qreg[4];
    #pragma unroll
    for (int ks = 0; ks < 4; ++ks) {
        int kk8 = 2 * ks + h32;
        Qreg[ks] = *(bf16x8*)&smem[(kk8 * 128 + ((wv * 32 + (lane & 31)) ^ kk8)) * 8];
    }
    __syncthreads();                             // Q region (== buf0) free now
    // write tile 0 into buf0; issue tile-1 loads
    *(bf16x8*)&smem[kfo0] = st0;
    *(bf16x8*)&smem[kfo1] = st1;
    #pragma unroll
    for (int ds = 0; ds < 8; ++ds) {
        smem[kto0 + ds * 64] = st0[ds];
        smem[kto1 + ds * 64] = st1[ds];
    }
    st0 = *(const bf16x8*)(g0 + (size_t)64 * D_);
    st1 = *(const bf16x8*)(g1 + (size_t)64 * D_);

    f32x16 accO0, accO1;
    #pragma unroll
    for (int i = 0; i < 16; ++i) { accO0[i] = 0.f; accO1[i] = 0.f; }
    float lsp0 = 0.f, lsp1 = 0.f;
    const int prow16 = ((((lane & 7) << 2) | ((lane >> 3) & 3)) * 16) + h32 * 512;
    const float SCL = 0.18033688f;               // 0.125 * log2(e)

    int rb = 0;                                  // read-buffer base (shorts)
    for (int u0 = 0; u0 < T_; u0 += 64) {
        __syncthreads();          // everyone done with prev tile (buf rb^8192)
        const int wb = rb ^ 8192;

        // ---- S^T[64 keys x 32 t] = K Q^T  (from buf rb) ----
        f32x16 aS0, aS1;
        #pragma unroll
        for (int i = 0; i < 16; ++i) { aS0[i] = 0.f; aS1[i] = 0.f; }
        __builtin_amdgcn_s_setprio(1);
        #pragma unroll
        for (int ks = 0; ks < 4; ++ks) {
            int kk8 = 2 * ks + h32;
            bf16x8 k0 = *(bf16x8*)&smem[rb + (kk8 * 64 + ((lane & 31) ^ kk8)) * 8];
            bf16x8 k1 = *(bf16x8*)&smem[rb + (kk8 * 64 + ((32 + (lane & 31)) ^ kk8)) * 8];
            aS0 = __builtin_amdgcn_mfma_f32_32x32x16_bf16(k0, Qreg[ks], aS0, 0, 0, 0);
            aS1 = __builtin_amdgcn_mfma_f32_32x32x16_bf16(k1, Qreg[ks], aS1, 0, 0, 0);
        }
        __builtin_amdgcn_s_setprio(0);

        // ---- stage tile u0+64 into buf wb (regs loaded last iter) ----
        *(bf16x8*)&smem[wb + kfo0] = st0;
        *(bf16x8*)&smem[wb + kfo1] = st1;
        #pragma unroll
        for (int ds = 0; ds < 8; ++ds) {
            smem[wb + kto0 + ds * 64] = st0[ds];
            smem[wb + kto1 + ds * 64] = st1[ds];
        }
        // ---- issue loads for tile u0+128 (used next iteration) ----
        int un = u0 + 128; if (un >= T_) un = 0;   // tail: harmless dummy
        st0 = *(const bf16x8*)(g0 + (size_t)un * D_);
        st1 = *(const bf16x8*)(g1 + (size_t)un * D_);

        // ---- exp2; pack C-layout -> A-frags (overlaps the ds-writes above) ----
        bf16x8 af[4];
        #pragma unroll
        for (int tt = 0; tt < 2; ++tt) {
            const f32x16& a = tt ? aS1 : aS0;
            float p[16];
            #pragma unroll
            for (int r = 0; r < 16; r += 2) {
                p[r]     = __builtin_amdgcn_exp2f(a[r] * SCL);
                p[r + 1] = __builtin_amdgcn_exp2f(a[r + 1] * SCL);
                lsp0 += p[r];
                lsp1 += p[r + 1];
            }
            #pragma unroll
            for (int sub = 0; sub < 2; ++sub) {
                union { uint u[4]; bf16x8 v; } cv;
                #pragma unroll
                for (int dd = 0; dd < 4; ++dd)
                    cv.u[dd] = __builtin_amdgcn_perm(
                        __float_as_uint(p[sub * 8 + 2 * dd + 1]),
                        __float_as_uint(p[sub * 8 + 2 * dd]), 0x07060302u);
                af[tt * 2 + sub] = cv.v;
            }
        }

        // ---- O[32 t x 64 s] += P V  (from buf rb KTf) ----
        __builtin_amdgcn_s_setprio(1);
        #pragma unroll
        for (int c = 0; c < 4; ++c) {
            bf16x8 v0 = *(bf16x8*)&smem[rb + 4096 + c * 1024 + prow16 + 0];
            bf16x8 v1 = *(bf16x8*)&smem[rb + 4096 + c * 1024 + prow16 + 8];
            accO0 = __builtin_amdgcn_mfma_f32_32x32x16_bf16(af[c], v0, accO0, 0, 0, 0);
            accO1 = __builtin_amdgcn_mfma_f32_32x32x16_bf16(af[c], v1, accO1, 0, 0, 0);
        }
        __builtin_amdgcn_s_setprio(0);
        rb = wb;
    }

    // ---- denominators; 1.0039 compensates P truncation bias ----
    float lsp = lsp0 + lsp1;
    float dsum = lsp + __shfl_xor(lsp, 32);
    short* ob = o + (size_t)b * (T_ * D_) + hh * S_;
    #pragma unroll
    for (int r = 0; r < 16; ++r) {
        int rt = (r & 3) + 8 * (r >> 2) + 4 * h32;
        float inv = 1.00390625f / __shfl(dsum, rt);
        size_t t = (size_t)(t0 + wv * 32 + rt);
        ob[t * D_ + (lane & 31)]      = f2bf(accO0[r] * inv);
        ob[t * D_ + 32 + (lane & 31)] = f2bf(accO1[r] * inv);
    }
}

extern "C" void kernel_launch(void* const* d_in, const int* in_sizes, int n_in,
                              void* d_out, int out_size, void* d_ws, size_t ws_size,
                              hipStream_t stream) {
    const float* x  = (const float*)d_in[0];
    const float* Wq = (const float*)d_in[1];
    const float* Wu = (const float*)d_in[2];
    const float* bu = (const float*)d_in[3];
    float* out  = (float*)d_out;
    short* qbuf = (short*)d_out;                          // bf16 q, bytes [0,16.8M)
    short* xb   = (short*)((char*)d_out + 16777216);      // bf16 x, bytes [16.8M,33.5M)
    short* attn = (short*)d_ws;                           // bf16 attn out (16.8 MB)
    short* wqb  = (short*)((char*)d_ws + 16777216);       // bf16 Wq (2 MB)
    short* wub  = (short*)((char*)d_ws + 18874368);       // bf16 Wu (2 MB)

    const int M = B_ * T_;
    dim3 blk(256);
    dim3 gg(D_ / 64, M / 128);                            // 128x64 tiles: (16,64)
    // 0) bf16 conversions (x, Wq, Wu) in one launch
    hipLaunchKernelGGL(cvt3, dim3(5120), blk, 0, stream, x, Wq, Wu, xb, wqb, wub);
    // 1) q_bf16 = x_bf @ Wq_bf^T
    hipLaunchKernelGGL((gemm_bt<true>), gg, blk, 0, stream,
                       xb, wqb, (const float*)nullptr, (void*)qbuf, M, D_, D_);
    // 2) attn_bf16 = softmax(q q^T / 8) q
    hipLaunchKernelGGL(attn_mfma, dim3(T_ / 128, B_ * H_), blk, 0, stream, qbuf, attn);
    // 3) out = attn @ Wu_bf^T + bu   (fp32)
    hipLaunchKernelGGL((gemm_bt<false>), gg, blk, 0, stream,
                       attn, wub, bu, (void*)out, M, D_, D_);
}

// Round 5
// 245.213 us; speedup vs baseline: 1.1103x; 1.1103x over previous
//
#include <hip/hip_runtime.h>

#define B_ 4
#define T_ 2048
#define D_ 1024
#define H_ 16
#define S_ 64

typedef __attribute__((ext_vector_type(8))) short bf16x8;
typedef __attribute__((ext_vector_type(16))) float f32x16;
typedef unsigned int uint;

__device__ __forceinline__ short f2bf(float f) {
    union { float f; uint u; } v; v.f = f;
    uint r = v.u + 0x7fffu + ((v.u >> 16) & 1u);   // RNE
    return (short)(r >> 16);
}

// async global->LDS, 16B per lane; LDS dst = wave-uniform base + lane*16
__device__ __forceinline__ void gld16(const short* g, short* l) {
    __builtin_amdgcn_global_load_lds((const __attribute__((address_space(1))) void*)g,
                                     (__attribute__((address_space(3))) void*)l, 16, 0, 0);
}

// ---------------- fused fp32->bf16 prepass: x, Wq, Wu ----------------
__global__ __launch_bounds__(256) void cvt3(const float* __restrict__ x,
                                            const float* __restrict__ wq,
                                            const float* __restrict__ wu,
                                            short* __restrict__ xb,
                                            short* __restrict__ wqb,
                                            short* __restrict__ wub) {
    const int NX = B_ * T_ * D_ / 8;   // 1048576 8-elem units
    const int NW = D_ * D_ / 8;        // 131072
    int i = blockIdx.x * 256 + threadIdx.x;
    const float* src; short* dst; int off;
    if (i < NX)            { src = x;  dst = xb;  off = i; }
    else if (i < NX + NW)  { src = wq; dst = wqb; off = i - NX; }
    else                   { src = wu; dst = wub; off = i - NX - NW; }
    float4 a = *(const float4*)(src + (size_t)off * 8);
    float4 b = *(const float4*)(src + (size_t)off * 8 + 4);
    short o[8] = {f2bf(a.x), f2bf(a.y), f2bf(a.z), f2bf(a.w),
                  f2bf(b.x), f2bf(b.y), f2bf(b.z), f2bf(b.w)};
    *(bf16x8*)(dst + (size_t)off * 8) = *(bf16x8*)o;
}

// ---------------- bf16 MFMA GEMM, ONE barrier per K-step --------------------
// C[M,N] = A[M,K] @ Bt[N,K]^T (+bias). 128x128 tile, BK=32, 4 waves (2x2).
// 3-buffer rotation, 2-deep prefetch, ONE s_barrier per step:
//   vmcnt(4) -> barrier -> issue STAGE(t+2) into buf[(t+2)%3] -> read+MFMA t.
// Safe: buf[(t+2)%3] was last read at step t-1; the step-t barrier proves all
// waves finished step t-1's ds_reads before any DMA into it is issued.
// Rationale: r0/r1/r4 A/Bs show per-step fixed cost (barriers) dominates;
// attn (16 MFMA per 1 barrier) hits 739 TF, gemm (8 MFMA per 2 barriers) 235.
#define STAGE_G(t, bi) do {                                                       \
        int kk_ = (t) << 5;                                                       \
        gld16(Ap + (size_t)lane * K        + kk_ + wv * 8, &As[bi][(wv * 128) * 8]);      \
        gld16(Ap + (size_t)(64 + lane) * K + kk_ + wv * 8, &As[bi][(wv * 128 + 64) * 8]); \
        gld16(Bp + (size_t)lane * K        + kk_ + wv * 8, &Bs[bi][(wv * 128) * 8]);      \
        gld16(Bp + (size_t)(64 + lane) * K + kk_ + wv * 8, &Bs[bi][(wv * 128 + 64) * 8]); \
    } while (0)

template <bool OUT_BF16>
__global__ __launch_bounds__(256, 2) void gemm_bt(const short* __restrict__ A,
                                                  const short* __restrict__ Bt,
                                                  const float* __restrict__ bias,
                                                  void* __restrict__ Cv,
                                                  int M, int N, int K) {
    __shared__ short As[3][4096];   // 24 KB
    __shared__ short Bs[3][4096];   // 24 KB
    const int tid  = threadIdx.x;
    const int lane = tid & 63;
    const int wv   = tid >> 6;
    const int wm   = wv >> 1, wn = wv & 1;
    const int h32  = lane >> 5;

    // bijective XCD swizzle: each XCD owns nby/8 contiguous m-panels x all n.
    int bx = blockIdx.x, by = blockIdx.y;
    {
        const int nbx = gridDim.x, nby = gridDim.y;
        if ((nby & 7) == 0) {
            int f = blockIdx.x + nbx * blockIdx.y;
            int xcd = f & 7, slot = f >> 3;
            bx = slot % nbx;
            by = xcd * (nby >> 3) + slot / nbx;
        }
    }
    const int m0 = by * 128, n0 = bx * 128;
    const short* Ap = A + (size_t)m0 * K;
    const short* Bp = Bt + (size_t)n0 * K;

    f32x16 acc[2][2];
    #pragma unroll
    for (int i = 0; i < 2; ++i)
        #pragma unroll
        for (int j = 0; j < 2; ++j)
            #pragma unroll
            for (int r = 0; r < 16; ++r) acc[i][j][r] = 0.f;

    const int nt = K >> 5;           // 32 K-steps (K=1024)
    STAGE_G(0, 0);
    STAGE_G(1, 1);                   // 8 gld16/wave in flight (tiles 0,1)

    int bi = 0, bs = 2;              // bi = read buf (t%3), bs = stage buf ((t+2)%3)
    for (int t = 0; t < nt; ++t) {
        // tile t's 4 loads are the oldest outstanding
        if (t + 1 < nt) asm volatile("s_waitcnt vmcnt(4)" ::: "memory");
        else            asm volatile("s_waitcnt vmcnt(0)" ::: "memory");
        __builtin_amdgcn_s_barrier();   // tile t landed everywhere; buf bs free
        asm volatile("" ::: "memory");

        if (t + 2 < nt) STAGE_G(t + 2, bs);   // issue early: 2 steps to land

        const short* Ab = As[bi];
        const short* Bb = Bs[bi];
        #pragma unroll
        for (int ks2 = 0; ks2 < 2; ++ks2) {
            const int kk8 = ks2 * 2 + h32;
            bf16x8 af0  = *(bf16x8*)&Ab[(kk8 * 128 + wm * 64 + (lane & 31)) * 8];
            bf16x8 af1  = *(bf16x8*)&Ab[(kk8 * 128 + wm * 64 + 32 + (lane & 31)) * 8];
            bf16x8 bfr0 = *(bf16x8*)&Bb[(kk8 * 128 + wn * 64 + (lane & 31)) * 8];
            bf16x8 bfr1 = *(bf16x8*)&Bb[(kk8 * 128 + wn * 64 + 32 + (lane & 31)) * 8];
            acc[0][0] = __builtin_amdgcn_mfma_f32_32x32x16_bf16(af0, bfr0, acc[0][0], 0, 0, 0);
            acc[0][1] = __builtin_amdgcn_mfma_f32_32x32x16_bf16(af0, bfr1, acc[0][1], 0, 0, 0);
            acc[1][0] = __builtin_amdgcn_mfma_f32_32x32x16_bf16(af1, bfr0, acc[1][0], 0, 0, 0);
            acc[1][1] = __builtin_amdgcn_mfma_f32_32x32x16_bf16(af1, bfr1, acc[1][1], 0, 0, 0);
        }

        bi = (bi == 2) ? 0 : bi + 1;
        bs = (bs == 2) ? 0 : bs + 1;
    }

    #pragma unroll
    for (int mt = 0; mt < 2; ++mt) {
        #pragma unroll
        for (int nt2 = 0; nt2 < 2; ++nt2) {
            const int rbase = m0 + wm * 64 + mt * 32;
            const int col   = n0 + wn * 64 + nt2 * 32 + (lane & 31);
            float bv = 0.f;
            if (!OUT_BF16 && bias) bv = bias[col];
            #pragma unroll
            for (int r = 0; r < 16; ++r) {
                int row = rbase + (r & 3) + 8 * (r >> 2) + 4 * h32;
                if constexpr (OUT_BF16)
                    ((short*)Cv)[(size_t)row * N + col] = f2bf(acc[mt][nt2][r]);
                else
                    ((float*)Cv)[(size_t)row * N + col] = acc[mt][nt2][r] + bv;
            }
        }
    }
}

// ---------------- MFMA attention v5: VALU-trimmed softmax -------------------
// (unchanged from round 3/4 — clean attribution of the GEMM change)
__global__ __launch_bounds__(256, 3) void attn_mfma(const short* __restrict__ q,
                                                    short* __restrict__ o) {
    __shared__ short smem[16384];   // 32 KB: buf0=[0,8192), buf1=[8192,16384) shorts
    const int tid  = threadIdx.x;
    const int lane = tid & 63;
    const int wv   = tid >> 6;
    const int h32  = lane >> 5;
    const int b  = blockIdx.y >> 4;
    const int hh = blockIdx.y & 15;
    const int t0 = blockIdx.x * 128;
    const short* qb = q + (size_t)b * (T_ * D_) + hh * S_;

    // tile-invariant staging geometry
    const int c8  = tid & 7;
    const int uu0 = tid >> 3;            // 0..31
    const int uu1 = uu0 + 32;            // 32..63
    const int u_0 = (uu0 & 0x33) | ((uu0 & 4) << 1) | ((uu0 & 8) >> 1);  // b2<->b3
    const int u_1 = (uu1 & 0x33) | ((uu1 & 4) << 1) | ((uu1 & 8) >> 1);
    const int kfo0 = (c8 * 64 + (u_0 ^ c8)) * 8;          // Kf within buffer
    const int kfo1 = (c8 * 64 + (u_1 ^ c8)) * 8;
    const int kto0 = 4096 + (u_0 >> 4) * 1024 + ((u_0 >> 2) & 1) * 512 + (c8 >> 2) * 8
                   + ((u_0 & 3) | (((u_0 >> 3) & 1) << 2)) + (c8 & 3) * 16;
    const int kto1 = 4096 + (u_1 >> 4) * 1024 + ((u_1 >> 2) & 1) * 512 + (c8 >> 2) * 8
                   + ((u_1 & 3) | (((u_1 >> 3) & 1) << 2)) + (c8 & 3) * 16;
    const short* g0 = qb + (size_t)u_0 * D_ + c8 * 8;
    const short* g1 = qb + (size_t)u_1 * D_ + c8 * 8;

    // ---- prologue: issue tile-0 loads, stage Q, read Q frags ----
    bf16x8 st0 = *(const bf16x8*)g0;            // tile 0 (u0 = 0)
    bf16x8 st1 = *(const bf16x8*)g1;
    #pragma unroll
    for (int rep = 0; rep < 4; ++rep) {
        int f = rep * 256 + tid;
        int r = f >> 3, cq = f & 7;
        bf16x8 v = *(const bf16x8*)(qb + (size_t)(t0 + r) * D_ + cq * 8);
        *(bf16x8*)&smem[(cq * 128 + (r ^ cq)) * 8] = v;
    }
    __syncthreads();
    bf16x8 Qreg[4];
    #pragma unroll
    for (int ks = 0; ks < 4; ++ks) {
        int kk8 = 2 * ks + h32;
        Qreg[ks] = *(bf16x8*)&smem[(kk8 * 128 + ((wv * 32 + (lane & 31)) ^ kk8)) * 8];
    }
    __syncthreads();                             // Q region (== buf0) free now
    // write tile 0 into buf0; issue tile-1 loads
    *(bf16x8*)&smem[kfo0] = st0;
    *(bf16x8*)&smem[kfo1] = st1;
    #pragma unroll
    for (int ds = 0; ds < 8; ++ds) {
        smem[kto0 + ds * 64] = st0[ds];
        smem[kto1 + ds * 64] = st1[ds];
    }
    st0 = *(const bf16x8*)(g0 + (size_t)64 * D_);
    st1 = *(const bf16x8*)(g1 + (size_t)64 * D_);

    f32x16 accO0, accO1;
    #pragma unroll
    for (int i = 0; i < 16; ++i) { accO0[i] = 0.f; accO1[i] = 0.f; }
    float lsp0 = 0.f, lsp1 = 0.f;
    const int prow16 = ((((lane & 7) << 2) | ((lane >> 3) & 3)) * 16) + h32 * 512;
    const float SCL = 0.18033688f;               // 0.125 * log2(e)

    int rb = 0;                                  // read-buffer base (shorts)
    for (int u0 = 0; u0 < T_; u0 += 64) {
        __syncthreads();          // everyone done with prev tile (buf rb^8192)
        const int wb = rb ^ 8192;

        // ---- S^T[64 keys x 32 t] = K Q^T  (from buf rb) ----
        f32x16 aS0, aS1;
        #pragma unroll
        for (int i = 0; i < 16; ++i) { aS0[i] = 0.f; aS1[i] = 0.f; }
        __builtin_amdgcn_s_setprio(1);
        #pragma unroll
        for (int ks = 0; ks < 4; ++ks) {
            int kk8 = 2 * ks + h32;
            bf16x8 k0 = *(bf16x8*)&smem[rb + (kk8 * 64 + ((lane & 31) ^ kk8)) * 8];
            bf16x8 k1 = *(bf16x8*)&smem[rb + (kk8 * 64 + ((32 + (lane & 31)) ^ kk8)) * 8];
            aS0 = __builtin_amdgcn_mfma_f32_32x32x16_bf16(k0, Qreg[ks], aS0, 0, 0, 0);
            aS1 = __builtin_amdgcn_mfma_f32_32x32x16_bf16(k1, Qreg[ks], aS1, 0, 0, 0);
        }
        __builtin_amdgcn_s_setprio(0);

        // ---- stage tile u0+64 into buf wb (regs loaded last iter) ----
        *(bf16x8*)&smem[wb + kfo0] = st0;
        *(bf16x8*)&smem[wb + kfo1] = st1;
        #pragma unroll
        for (int ds = 0; ds < 8; ++ds) {
            smem[wb + kto0 + ds * 64] = st0[ds];
            smem[wb + kto1 + ds * 64] = st1[ds];
        }
        // ---- issue loads for tile u0+128 (used next iteration) ----
        int un = u0 + 128; if (un >= T_) un = 0;   // tail: harmless dummy
        st0 = *(const bf16x8*)(g0 + (size_t)un * D_);
        st1 = *(const bf16x8*)(g1 + (size_t)un * D_);

        // ---- exp2; pack C-layout -> A-frags (overlaps the ds-writes above) ----
        bf16x8 af[4];
        #pragma unroll
        for (int tt = 0; tt < 2; ++tt) {
            const f32x16& a = tt ? aS1 : aS0;
            float p[16];
            #pragma unroll
            for (int r = 0; r < 16; r += 2) {
                p[r]     = __builtin_amdgcn_exp2f(a[r] * SCL);
                p[r + 1] = __builtin_amdgcn_exp2f(a[r + 1] * SCL);
                lsp0 += p[r];
                lsp1 += p[r + 1];
            }
            #pragma unroll
            for (int sub = 0; sub < 2; ++sub) {
                union { uint u[4]; bf16x8 v; } cv;
                #pragma unroll
                for (int dd = 0; dd < 4; ++dd)
                    cv.u[dd] = __builtin_amdgcn_perm(
                        __float_as_uint(p[sub * 8 + 2 * dd + 1]),
                        __float_as_uint(p[sub * 8 + 2 * dd]), 0x07060302u);
                af[tt * 2 + sub] = cv.v;
            }
        }

        // ---- O[32 t x 64 s] += P V  (from buf rb KTf) ----
        __builtin_amdgcn_s_setprio(1);
        #pragma unroll
        for (int c = 0; c < 4; ++c) {
            bf16x8 v0 = *(bf16x8*)&smem[rb + 4096 + c * 1024 + prow16 + 0];
            bf16x8 v1 = *(bf16x8*)&smem[rb + 4096 + c * 1024 + prow16 + 8];
            accO0 = __builtin_amdgcn_mfma_f32_32x32x16_bf16(af[c], v0, accO0, 0, 0, 0);
            accO1 = __builtin_amdgcn_mfma_f32_32x32x16_bf16(af[c], v1, accO1, 0, 0, 0);
        }
        __builtin_amdgcn_s_setprio(0);
        rb = wb;
    }

    // ---- denominators; 1.0039 compensates P truncation bias ----
    float lsp = lsp0 + lsp1;
    float dsum = lsp + __shfl_xor(lsp, 32);
    short* ob = o + (size_t)b * (T_ * D_) + hh * S_;
    #pragma unroll
    for (int r = 0; r < 16; ++r) {
        int rt = (r & 3) + 8 * (r >> 2) + 4 * h32;
        float inv = 1.00390625f / __shfl(dsum, rt);
        size_t t = (size_t)(t0 + wv * 32 + rt);
        ob[t * D_ + (lane & 31)]      = f2bf(accO0[r] * inv);
        ob[t * D_ + 32 + (lane & 31)] = f2bf(accO1[r] * inv);
    }
}

extern "C" void kernel_launch(void* const* d_in, const int* in_sizes, int n_in,
                              void* d_out, int out_size, void* d_ws, size_t ws_size,
                              hipStream_t stream) {
    const float* x  = (const float*)d_in[0];
    const float* Wq = (const float*)d_in[1];
    const float* Wu = (const float*)d_in[2];
    const float* bu = (const float*)d_in[3];
    float* out  = (float*)d_out;
    short* qbuf = (short*)d_out;                          // bf16 q, bytes [0,16.8M)
    short* xb   = (short*)((char*)d_out + 16777216);      // bf16 x, bytes [16.8M,33.5M)
    short* attn = (short*)d_ws;                           // bf16 attn out (16.8 MB)
    short* wqb  = (short*)((char*)d_ws + 16777216);       // bf16 Wq (2 MB)
    short* wub  = (short*)((char*)d_ws + 18874368);       // bf16 Wu (2 MB)

    const int M = B_ * T_;
    dim3 blk(256);
    dim3 gg(D_ / 128, M / 128);                           // 128x128 tiles: (8,64)
    // 0) bf16 conversions (x, Wq, Wu) in one launch
    hipLaunchKernelGGL(cvt3, dim3(5120), blk, 0, stream, x, Wq, Wu, xb, wqb, wub);
    // 1) q_bf16 = x_bf @ Wq_bf^T
    hipLaunchKernelGGL((gemm_bt<true>), gg, blk, 0, stream,
                       xb, wqb, (const float*)nullptr, (void*)qbuf, M, D_, D_);
    // 2) attn_bf16 = softmax(q q^T / 8) q
    hipLaunchKernelGGL(attn_mfma, dim3(T_ / 128, B_ * H_), blk, 0, stream, qbuf, attn);
    // 3) out = attn @ Wu_bf^T + bu   (fp32)
    hipLaunchKernelGGL((gemm_bt<false>), gg, blk, 0, stream,
                       attn, wub, bu, (void*)out, M, D_, D_);
}